// Round 15
// baseline (42.995 us; speedup 1.0000x reference)
//
#include <hip/hip_runtime.h>

#define S 128
#define SS (S*S)
#define B 8
#define BSS (B*SS)              // 131072 floats per [b][128][128] stack
#define NEG_INF (-3.402823466e+38f)

// ws layout (float elements). NO global atomics on maps, NO memset.
// ACC_LOSS: [b][quarter] topo partials (32)
// ACC_DICE: [bid(256)][{at,aa,tt}] (768)
// ACC_CNT : pool completion counter (1 uint, re-zeroed by proj each launch)
// PA : [vol][b][i][j]  exact                 (2*BSS)
// PBP: [vol][b][ic=8][j][k] partials         (2*8*8*SS)
// PCP: [vol][b][jc=4][i][k] partials         (2*8*4*SS)
#define ACC_LOSS 0
#define ACC_DICE 32
#define ACC_CNT  1008
#define PA   1024
#define PBP  (PA  + 2*BSS)
#define PCP  (PBP + 2*8*8*SS)

__device__ __forceinline__ float4 max4(float4 a, float4 b) {
  return make_float4(fmaxf(a.x,b.x), fmaxf(a.y,b.y), fmaxf(a.z,b.z), fmaxf(a.w,b.w));
}
__device__ __forceinline__ float hmax4(float4 a) {
  return fmaxf(fmaxf(a.x,a.y), fmaxf(a.z,a.w));
}
__device__ __forceinline__ float4 shflx4(float4 v, int m) {
  return make_float4(__shfl_xor(v.x,m,64), __shfl_xor(v.y,m,64),
                     __shfl_xor(v.z,m,64), __shfl_xor(v.w,m,64));
}

// Phase 1: stream channel-1 of both volumes once; projections + dice sums.
// R8/R14 structure (best measured) with ONE delta: Pa row-maxes buffered in
// LDS (lpa) and flushed coalesced in the tail, replacing the in-loop
// scattered dword stores (each hit its own 64B sector -> ~16 MB write waste
// + L2 RMW fills). Everything else byte-identical to R14.
__global__ __launch_bounds__(1024, 4) void proj_dice_kernel(
    const float* __restrict__ gin, const float* __restrict__ gtg,
    float* __restrict__ ws)
{
  const int jc  = blockIdx.x;   // 0..3   j chunk of 32
  const int ic  = blockIdx.y;   // 0..7   i chunk of 16
  const int b   = blockIdx.z;   // 0..7
  const int tid = threadIdx.x;
  const int jr  = tid >> 5;     // 0..31
  const int kl  = tid & 31;     // 0..31
  const int j   = (jc << 5) + jr;
  const int i0  = ic << 4;
  const int k0  = kl << 2;
  const int w   = tid >> 6;     // wave 0..15
  const int h   = (tid >> 5) & 1;

  // re-arm the pool completion counter every launch (visible to the pool
  // dispatch via the dispatch boundary; solves poison-init determinism).
  if (tid == 0 && jc == 0 && ic == 0 && b == 0)
    ((unsigned*)ws)[ACC_CNT] = 0u;

  const float* __restrict__ xin = gin + (size_t)(2*b + 1) * (size_t)(S*SS);
  const float* __restrict__ xtg = gtg + (size_t)(2*b + 1) * (size_t)(S*SS);

  float* paI = ws + PA + (size_t)(0*B + b)*SS;
  float* paT = ws + PA + (size_t)(1*B + b)*SS;
  float* pbI = ws + PBP + (size_t)((0*B + b)*8 + ic)*SS;
  float* pbT = ws + PBP + (size_t)((1*B + b)*8 + ic)*SS;
  float* pcI = ws + PCP + (size_t)((0*B + b)*4 + jc)*SS;
  float* pcT = ws + PCP + (size_t)((1*B + b)*4 + jc)*SS;

  __shared__ float lpc[2][4][2][16][S];   // 128 KB: [parity][q][tensor][wave][k]
  __shared__ float lpa[2][16][32];        //   4 KB: [tensor][ii][jr] Pa maxes
  __shared__ float dred[16][3];

  float4 pba = make_float4(NEG_INF, NEG_INF, NEG_INF, NEG_INF);
  float4 pbt = pba;
  float s_at = 0.f, s_aa = 0.f, s_tt = 0.f;

  for (int r = 0; r < 4; ++r) {
    const int par = r & 1;
    #pragma unroll
    for (int q = 0; q < 4; ++q) {
      const int ii = (r << 2) + q;
      const int i  = i0 + ii;
      const size_t off = (size_t)i*SS + (size_t)j*S + k0;
      const float4 a = *(const float4*)(xin + off);
      const float4 t = *(const float4*)(xtg + off);

      s_at = fmaf(a.x,t.x, fmaf(a.y,t.y, fmaf(a.z,t.z, fmaf(a.w,t.w, s_at))));
      s_aa = fmaf(a.x,a.x, fmaf(a.y,a.y, fmaf(a.z,a.z, fmaf(a.w,a.w, s_aa))));
      s_tt = fmaf(t.x,t.x, fmaf(t.y,t.y, fmaf(t.z,t.z, fmaf(t.w,t.w, s_tt))));

      // Pb accumulate over i (register)
      pba = max4(pba, a);
      pbt = max4(pbt, t);

      // Pa[i][j]: max over k = 32 kl lanes of this half-wave -> LDS buffer
      float rma = hmax4(a), rmt = hmax4(t);
      #pragma unroll
      for (int m = 16; m >= 1; m >>= 1) {
        rma = fmaxf(rma, __shfl_xor(rma, m, 64));
        rmt = fmaxf(rmt, __shfl_xor(rmt, m, 64));
      }
      if (kl == 0) { lpa[0][ii][jr] = rma; lpa[1][ii][jr] = rmt; }

      // Pc wave partial: combine the wave's jr-pair, stash in LDS
      const float4 pca = max4(a, shflx4(a, 32));
      const float4 pct = max4(t, shflx4(t, 32));
      if (h == 0) {
        *(float4*)&lpc[par][q][0][w][k0] = pca;
        *(float4*)&lpc[par][q][1][w][k0] = pct;
      }
    }
    __syncthreads();
    {
      // tail: 1024 threads = 4 q x 2 tensors x 128 k -> plain store partial
      const int q  = tid >> 8;
      const int t  = (tid >> 7) & 1;
      const int k  = tid & 127;
      float m = lpc[par][q][t][0][k];
      #pragma unroll
      for (int rr = 1; rr < 16; ++rr) m = fmaxf(m, lpc[par][q][t][rr][k]);
      const int i = i0 + (r << 2) + q;
      (t ? pcT : pcI)[i*S + k] = m;
    }
    // no second barrier: next round writes the other parity half.
  }

  // Pa flush: 2t x 16ii x 32jj = 1024 coalesced dwords (32-dword runs).
  // The r=3 __syncthreads() above ordered all lpa writes.
  {
    const int t  = tid >> 9;
    const int ii = (tid >> 5) & 15;
    const int jj = tid & 31;
    (t ? paT : paI)[(size_t)(i0+ii)*S + (jc << 5) + jj] = lpa[t][ii][jj];
  }

  // flush Pb partial [j][k] (max over this block's 16 i's)
  *(float4*)(pbI + j*S + k0) = pba;
  *(float4*)(pbT + j*S + k0) = pbt;

  // dice partial: wave-reduce then per-block plain store (no atomics)
  float v0 = s_at, v1 = s_aa, v2 = s_tt;
  #pragma unroll
  for (int m = 32; m >= 1; m >>= 1) {
    v0 += __shfl_xor(v0, m, 64);
    v1 += __shfl_xor(v1, m, 64);
    v2 += __shfl_xor(v2, m, 64);
  }
  if ((tid & 63) == 0) { dred[w][0] = v0; dred[w][1] = v1; dred[w][2] = v2; }
  __syncthreads();
  if (tid == 0) {
    float a0 = 0.f, a1 = 0.f, a2 = 0.f;
    #pragma unroll
    for (int rr = 0; rr < 16; ++rr) { a0 += dred[rr][0]; a1 += dred[rr][1]; a2 += dred[rr][2]; }
    const int bid = jc + 4*ic + 32*b;   // 32 blocks per b
    ws[ACC_DICE + bid*3 + 0] = a0;
    ws[ACC_DICE + bid*3 + 1] = a1;
    ws[ACC_DICE + bid*3 + 2] = a2;
  }
}

// Phase 2: fused partial-reduce + pyramid max-pool + (last block) finalize.
// Grid (quarter=4, b=8) = 32 blocks, 64 threads (1 wave). Each block owns a
// 128x32 column-quarter (all pooling windows <=32 cols stay inside it).
// Lane = (tr = lane>>2 in 0..15, tc = lane&3), owns an 8x8 tile.
// k=2,4,8 in-registers; k=16 via shfl_xor {1,4}; k=32 via {2,8}.
// Last block to finish (agent-scope acq_rel counter) does dice finalize +
// output write — release/acquire gives cross-XCD visibility.
__global__ __launch_bounds__(64) void pool_loss_kernel(
    float* __restrict__ ws, float* __restrict__ out)
{
  const int quarter = blockIdx.x;   // 0..3
  const int b       = blockIdx.y;
  const int tid     = threadIdx.x;  // 0..63
  const int tr      = tid >> 2;     // 0..15
  const int tc      = tid & 3;      // 0..3
  const int r0      = tr << 3;
  const int c0      = (quarter << 5) + (tc << 3);

  float s2[2][4][4];
  float s4[2][2][2];
  float s8[2], s16[2], s32[2];
  #pragma unroll
  for (int v = 0; v < 2; ++v) {
    #pragma unroll
    for (int y = 0; y < 4; ++y)
      #pragma unroll
      for (int x = 0; x < 4; ++x) s2[v][y][x] = 0.f;
    #pragma unroll
    for (int y = 0; y < 2; ++y)
      #pragma unroll
      for (int x = 0; x < 2; ++x) s4[v][y][x] = 0.f;
    s8[v] = 0.f; s16[v] = 0.f; s32[v] = 0.f;
  }

  #pragma unroll
  for (int t = 0; t < 3; ++t) {
    #pragma unroll
    for (int vol = 0; vol < 2; ++vol) {
      const int np = (t == 0) ? 1 : (t == 1) ? 8 : 4;
      const float* base =
        (t == 0) ? ws + PA  + (size_t)(vol*B + b)*SS :
        (t == 1) ? ws + PBP + (size_t)((vol*B + b)*8)*SS :
                   ws + PCP + (size_t)((vol*B + b)*4)*SS;
      float tile[8][8];
      #pragma unroll
      for (int r = 0; r < 8; ++r)
        #pragma unroll
        for (int c = 0; c < 8; ++c) tile[r][c] = NEG_INF;
      for (int p = 0; p < np; ++p) {
        const float* m = base + (size_t)p*SS;
        #pragma unroll
        for (int r = 0; r < 8; ++r) {
          const float4 a = *(const float4*)(m + (size_t)(r0 + r)*S + c0);
          const float4 c = *(const float4*)(m + (size_t)(r0 + r)*S + c0 + 4);
          tile[r][0]=fmaxf(tile[r][0],a.x); tile[r][1]=fmaxf(tile[r][1],a.y);
          tile[r][2]=fmaxf(tile[r][2],a.z); tile[r][3]=fmaxf(tile[r][3],a.w);
          tile[r][4]=fmaxf(tile[r][4],c.x); tile[r][5]=fmaxf(tile[r][5],c.y);
          tile[r][6]=fmaxf(tile[r][6],c.z); tile[r][7]=fmaxf(tile[r][7],c.w);
        }
      }
      float m2[4][4];
      #pragma unroll
      for (int y = 0; y < 4; ++y)
        #pragma unroll
        for (int x = 0; x < 4; ++x) {
          m2[y][x] = fmaxf(fmaxf(tile[2*y][2*x], tile[2*y][2*x+1]),
                           fmaxf(tile[2*y+1][2*x], tile[2*y+1][2*x+1]));
          s2[vol][y][x] += m2[y][x];
        }
      float m4[2][2];
      #pragma unroll
      for (int y = 0; y < 2; ++y)
        #pragma unroll
        for (int x = 0; x < 2; ++x) {
          m4[y][x] = fmaxf(fmaxf(m2[2*y][2*x], m2[2*y][2*x+1]),
                           fmaxf(m2[2*y+1][2*x], m2[2*y+1][2*x+1]));
          s4[vol][y][x] += m4[y][x];
        }
      float m8 = fmaxf(fmaxf(m4[0][0], m4[0][1]), fmaxf(m4[1][0], m4[1][1]));
      s8[vol] += m8;
      float m16 = m8;                           // 16x16: partners tc^1, tr^1
      m16 = fmaxf(m16, __shfl_xor(m16, 1, 64));
      m16 = fmaxf(m16, __shfl_xor(m16, 4, 64));
      s16[vol] += m16;
      float m32 = m16;                          // 32x32: +tc^2, tr^2
      m32 = fmaxf(m32, __shfl_xor(m32, 2, 64));
      m32 = fmaxf(m32, __shfl_xor(m32, 8, 64));
      s32[vol] += m32;
    }
  }

  const float w0 = 1.f/(5.f*8.f*64.f*64.f);
  const float w1 = 1.f/(5.f*8.f*32.f*32.f);
  const float w2 = 1.f/(5.f*8.f*16.f*16.f);
  const float w3 = 1.f/(5.f*8.f*8.f*8.f);
  const float w4 = 1.f/(5.f*8.f*4.f*4.f);

  float l0 = 0.f;
  #pragma unroll
  for (int y = 0; y < 4; ++y)
    #pragma unroll
    for (int x = 0; x < 4; ++x) l0 += fabsf(s2[1][y][x] - s2[0][y][x]);
  float l1 = 0.f;
  #pragma unroll
  for (int y = 0; y < 2; ++y)
    #pragma unroll
    for (int x = 0; x < 2; ++x) l1 += fabsf(s4[1][y][x] - s4[0][y][x]);
  float part = l0*w0 + l1*w1 + fabsf(s8[1] - s8[0])*w2;
  if ((tid & 0x05) == 0) part += fabsf(s16[1] - s16[0])*w3;   // tc,tr even
  if ((tid & 0x0F) == 0) part += fabsf(s32[1] - s32[0])*w4;   // tc==0, tr%4==0

  #pragma unroll
  for (int m = 32; m >= 1; m >>= 1) part += __shfl_xor(part, m, 64);
  __shared__ int isLast;
  if (tid == 0) {
    ws[ACC_LOSS + (b << 2) + quarter] = part;
    // release own stores + count completion (agent scope = device-wide)
    unsigned old = __hip_atomic_fetch_add((unsigned*)ws + ACC_CNT, 1u,
                                          __ATOMIC_ACQ_REL,
                                          __HIP_MEMORY_SCOPE_AGENT);
    isLast = (old == 31u);
  }
  __syncthreads();
  if (!isLast) return;

  // ---- finalize (last pool block only; acquire above makes all other
  //      blocks' ACC_LOSS stores + proj's ACC_DICE stores visible) ----
  __shared__ float fd[8];
  {
    const int bf  = tid >> 3;       // 0..7
    const int g   = tid & 7;        // 0..7
    const int bid = (bf << 5) + (g << 2);
    float v0 = 0.f, v1 = 0.f, v2 = 0.f;
    #pragma unroll
    for (int u = 0; u < 4; ++u) {
      v0 += ws[ACC_DICE + (bid+u)*3 + 0];
      v1 += ws[ACC_DICE + (bid+u)*3 + 1];
      v2 += ws[ACC_DICE + (bid+u)*3 + 2];
    }
    #pragma unroll
    for (int m = 4; m >= 1; m >>= 1) {
      v0 += __shfl_xor(v0, m, 64);
      v1 += __shfl_xor(v1, m, 64);
      v2 += __shfl_xor(v2, m, 64);
    }
    if (g == 0) fd[bf] = (2.f*v0 + 1e-6f) / (v1 + v2);
  }
  __syncthreads();
  if (tid == 0) {
    float topo = 0.f, dsum = 0.f;
    #pragma unroll
    for (int x = 0; x < 32; ++x) topo += ws[ACC_LOSS + x];
    #pragma unroll
    for (int bb = 0; bb < B; ++bb) dsum += fd[bb];
    out[0] = topo + (1.f - dsum / (float)B);
  }
}

extern "C" void kernel_launch(void* const* d_in, const int* in_sizes, int n_in,
                              void* d_out, int out_size, void* d_ws, size_t ws_size,
                              hipStream_t stream)
{
  const float* gin = (const float*)d_in[0];
  const float* gtg = (const float*)d_in[1];
  float* ws  = (float*)d_ws;
  float* out = (float*)d_out;

  dim3 g1(4, 8, B);
  proj_dice_kernel<<<g1, dim3(1024), 0, stream>>>(gin, gtg, ws);

  pool_loss_kernel<<<dim3(4, B), dim3(64), 0, stream>>>(ws, out);
}